// Round 2
// 745.131 us; speedup vs baseline: 1.0765x; 1.0765x over previous
//
#include <hip/hip_runtime.h>
#include <hip/hip_bf16.h>
#include <math.h>

#define N_TOK 8192
#define DIM   1024
#define NEXP  8
#define FDIM  2752
#define BK    64
#define MT    128
#define NT    128
#define WGU_ROWS 5504          // 2*FDIM interleaved rows per expert
#define NT2   (DIM / BK)       // 16 K-tiles for gemm_a

typedef __bf16 v8bf __attribute__((ext_vector_type(8)));
typedef __bf16 v4bf __attribute__((ext_vector_type(4)));
typedef float  v4f  __attribute__((ext_vector_type(4)));

// ws layout (bytes)
#define WS_HDR     0                // int[64]: [0..7]=counts [8..15]=cursor [16..24]=poff (poff[8]=total)
#define WS_LOADSUM 256              // float[8]
#define WS_IDS     512              // int[2*N_TOK]  (after scatter: holds SLOT per (tok,k))
#define WS_PROBS   66048            // float[2*N_TOK]
#define WS_PERM    131584           // int[17408]
#define WS_WGT     201216           // float[17408]
#define WS_H       270848           // bf16[17408*FDIM] = 95,813,632 B
#define WS_XBF     96084480ull      // bf16[N_TOK*DIM]
#define WS_WGU     112861696ull     // bf16[8*WGU_ROWS*DIM] = 90,177,536 B (interleaved g/u)
#define WS_WD_T    203039232ull     // bf16[8*FDIM*DIM] = 45,088,768 B
#define WS_Y       112861696ull     // fp32[17408*1024] = 71,303,168 B, overlays WGU (dead after gemm_a)

__device__ __forceinline__ void gld16(const __bf16* g, __bf16* l) {
    __builtin_amdgcn_global_load_lds(
        (const __attribute__((address_space(1))) void*)g,
        (__attribute__((address_space(3))) void*)l, 16, 0, 0);
}

// ---------------- gating (grid-stride: 256 blocks x 8 passes) ----------------
__global__ __launch_bounds__(256) void gate_kernel(
    const float* __restrict__ x, const float* __restrict__ gw,
    int* __restrict__ hdr, float* __restrict__ load_sum,
    int* __restrict__ ids, float* __restrict__ probs, __bf16* __restrict__ xb)
{
    __shared__ float s_load[NEXP];
    __shared__ int   s_cnt[NEXP];
    int tid = threadIdx.x;
    if (tid < NEXP) { s_load[tid] = 0.f; s_cnt[tid] = 0; }
    __syncthreads();

    int wave = tid >> 6, lane = tid & 63;
#pragma unroll 1
    for (int pass = 0; pass < 8; ++pass) {
        int tok = (blockIdx.x * 8 + pass) * 4 + wave;
        float acc[NEXP];
#pragma unroll
        for (int e = 0; e < NEXP; e++) acc[e] = 0.f;
        const float4* xr4 = (const float4*)(x + (size_t)tok * DIM);
#pragma unroll
        for (int it = 0; it < 4; it++) {
            int d4 = it * 64 + lane;
            float4 xv = xr4[d4];
            v4bf vb;
            vb[0] = (__bf16)xv.x; vb[1] = (__bf16)xv.y;
            vb[2] = (__bf16)xv.z; vb[3] = (__bf16)xv.w;
            *(v4bf*)&xb[(size_t)tok * DIM + d4 * 4] = vb;
            int d = d4 * 4;
#pragma unroll
            for (int e = 0; e < NEXP; e++)
                acc[e] += xv.x * gw[d * NEXP + e] + xv.y * gw[(d + 1) * NEXP + e]
                        + xv.z * gw[(d + 2) * NEXP + e] + xv.w * gw[(d + 3) * NEXP + e];
        }
#pragma unroll
        for (int e = 0; e < NEXP; e++) {
#pragma unroll
            for (int off = 32; off > 0; off >>= 1) acc[e] += __shfl_xor(acc[e], off, 64);
        }
        if (lane == 0) {
            float m = acc[0];
#pragma unroll
            for (int e = 1; e < NEXP; e++) m = fmaxf(m, acc[e]);
            float p[NEXP], s = 0.f;
#pragma unroll
            for (int e = 0; e < NEXP; e++) { p[e] = __expf(acc[e] - m); s += p[e]; }
            float inv = 1.f / s;
#pragma unroll
            for (int e = 0; e < NEXP; e++) p[e] *= inv;
            int i1 = 0; float p1 = p[0];
#pragma unroll
            for (int e = 1; e < NEXP; e++) if (p[e] > p1) { p1 = p[e]; i1 = e; }
            int i2 = -1; float p2 = -1.f;
#pragma unroll
            for (int e = 0; e < NEXP; e++) if (e != i1 && p[e] > p2) { p2 = p[e]; i2 = e; }
            float rs = 1.f / (p1 + p2 + 1e-8f);
            ids[tok * 2] = i1;  ids[tok * 2 + 1] = i2;
            probs[tok * 2] = p1 * rs;  probs[tok * 2 + 1] = p2 * rs;
#pragma unroll
            for (int e = 0; e < NEXP; e++) atomicAdd(&s_load[e], p[e]);
            atomicAdd(&s_cnt[i1], 1);  atomicAdd(&s_cnt[i2], 1);
        }
    }
    __syncthreads();
    if (tid < NEXP) {
        atomicAdd(&load_sum[tid], s_load[tid]);
        atomicAdd(&hdr[tid], s_cnt[tid]);
    }
}

// ---------------- scan ----------------
__global__ void scan_kernel(int* __restrict__ hdr, const float* __restrict__ load_sum,
                            float* __restrict__ aux_out)
{
    if (threadIdx.x == 0) {
        int off = 0;
        float aux = 0.f;
        for (int e = 0; e < NEXP; e++) {
            hdr[16 + e] = off;
            int c = hdr[e];
            off += (c + 127) & ~127;
            aux += ((float)c / (float)(N_TOK * 2)) * (load_sum[e] / (float)N_TOK);
        }
        hdr[24] = off;
        *aux_out = 0.01f * 8.f * aux;
    }
}

// ---------------- scatter: LDS-aggregated cursors ----------------
__global__ __launch_bounds__(256) void scatter_kernel(
    const int* __restrict__ probs_dummy, const float* __restrict__ probs,
    int* __restrict__ hdr, int* __restrict__ perm, float* __restrict__ wgt,
    int* __restrict__ ids)
{
    __shared__ int s_cnt[NEXP], s_base[NEXP];
    int tid = threadIdx.x;
    if (tid < NEXP) s_cnt[tid] = 0;
    __syncthreads();
    int t = blockIdx.x * 256 + tid;
    int e0 = ids[t * 2], e1 = ids[t * 2 + 1];
    int l0 = atomicAdd(&s_cnt[e0], 1);
    int l1 = atomicAdd(&s_cnt[e1], 1);
    __syncthreads();
    if (tid < NEXP) s_base[tid] = atomicAdd(&hdr[8 + tid], s_cnt[tid]);
    __syncthreads();
    int s0 = hdr[16 + e0] + s_base[e0] + l0;
    int s1 = hdr[16 + e1] + s_base[e1] + l1;
    perm[s0] = t;  wgt[s0] = probs[t * 2];
    perm[s1] = t;  wgt[s1] = probs[t * 2 + 1];
    ids[t * 2] = s0;  ids[t * 2 + 1] = s1;
}

// ---------------- transpose+cast ----------------
__device__ __forceinline__ void tc_body(const float* __restrict__ s, __bf16* __restrict__ d,
                                        int R, int C, int cb, int rb, int tid)
{
    __shared__ float tile[64][65];
    int c4 = (tid & 15) * 4, rr = tid >> 4;
#pragma unroll
    for (int p = 0; p < 4; p++) {
        int r = p * 16 + rr;
        float4 v = *(const float4*)&s[(size_t)(rb + r) * C + cb + c4];
        tile[r][c4] = v.x; tile[r][c4 + 1] = v.y; tile[r][c4 + 2] = v.z; tile[r][c4 + 3] = v.w;
    }
    __syncthreads();
#pragma unroll
    for (int p = 0; p < 2; p++) {
        int cc = p * 32 + (tid >> 3);
        int rr0 = (tid & 7) * 8;
        v8bf v;
#pragma unroll
        for (int j = 0; j < 8; j++) v[j] = (__bf16)tile[rr0 + j][cc];
        *(v8bf*)&d[(size_t)(cb + cc) * R + rb + rr0] = v;
    }
}

// wg/wu -> interleaved WGU: row(f, which) = (f>>4)*32 + (f&15) + which*16
__global__ __launch_bounds__(256) void transpose_gu(
    const float* __restrict__ wg, const float* __restrict__ wu,
    __bf16* __restrict__ wgu)
{
    int which = blockIdx.z >> 3, e = blockIdx.z & 7;
    const float* s = (which ? wu : wg) + (size_t)e * DIM * FDIM;
    __bf16* d = wgu + (size_t)e * WGU_ROWS * DIM;

    __shared__ float tile[64][65];
    int cb = blockIdx.x * 64, rb = blockIdx.y * 64, tid = threadIdx.x;
    int c4 = (tid & 15) * 4, rr = tid >> 4;
#pragma unroll
    for (int p = 0; p < 4; p++) {
        int r = p * 16 + rr;
        float4 v = *(const float4*)&s[(size_t)(rb + r) * FDIM + cb + c4];
        tile[r][c4] = v.x; tile[r][c4 + 1] = v.y; tile[r][c4 + 2] = v.z; tile[r][c4 + 3] = v.w;
    }
    __syncthreads();
#pragma unroll
    for (int p = 0; p < 2; p++) {
        int cc = p * 32 + (tid >> 3);
        int rr0 = (tid & 7) * 8;
        v8bf v;
#pragma unroll
        for (int j = 0; j < 8; j++) v[j] = (__bf16)tile[rr0 + j][cc];
        int f = cb + cc;
        int fr = ((f >> 4) << 5) + (f & 15) + which * 16;
        *(v8bf*)&d[(size_t)fr * DIM + rb + rr0] = v;
    }
}

__global__ __launch_bounds__(256) void transpose_d(
    const float* __restrict__ wd, __bf16* __restrict__ wdt)
{
    size_t slab = (size_t)blockIdx.z * DIM * FDIM;
    tc_body(wd + slab, wdt + slab, FDIM, DIM, blockIdx.x * 64, blockIdx.y * 64, threadIdx.x);
}

// ---------------- pass A: 8-phase counted-vmcnt schedule, BM=128 x BN=256(interleaved g|u) x BK=64 ----------------
// 8 waves (2M x 4N), quadrant phases: P1=(0,0) P2=(0,1) P3=(1,0) P4=(1,1)
// staging: P1->A1(t+1)[other buf], P2->A0(t+2)[cur], P3->B0(t+2)[cur], P4->B1(t+2)[cur]
// boundary s_waitcnt vmcnt(5) lands the entire next tile; drain vmcnt(0) only entering last tile.
#define STGA(Abase, ih) do { gld16(apg[ih], (Abase) + ((ih)*64 + wv*8)*BK); apg[ih] += BK; } while (0)
#define STGB(Bbase, hb) do { \
    gld16(bpg[hb][0], (Bbase) + ((hb)*128 + wv*16)*BK);     bpg[hb][0] += BK; \
    gld16(bpg[hb][1], (Bbase) + ((hb)*128 + wv*16 + 8)*BK); bpg[hb][1] += BK; } while (0)

__global__ __launch_bounds__(512, 1) void gemm_a8(
    const __bf16* __restrict__ xb, const __bf16* __restrict__ wgu,
    const int* __restrict__ hdr, const int* __restrict__ perm,
    __bf16* __restrict__ Hb)
{
    int mbase = blockIdx.y * MT;
    if (mbase >= hdr[24]) return;
    int e = 0;
    while (mbase >= hdr[17 + e]) e++;
    const __bf16* wb = wgu + (size_t)e * WGU_ROWS * DIM;
    int nbase = blockIdx.x * 256;       // interleaved row base
    int fbase = blockIdx.x * 128;       // F base

    __shared__ __align__(16) __bf16 lds[2][(MT + 256) * BK];   // 96 KiB

    int tid = threadIdx.x, wv = tid >> 6, ln = tid & 63;
    int srow = ln >> 3, sch = (ln & 7) ^ srow;

    const __bf16 *apg[2], *bpg[2][2];
#pragma unroll
    for (int ih = 0; ih < 2; ih++) {
        int row = ih * 64 + wv * 8 + srow;
        apg[ih] = xb + (size_t)perm[mbase + row] * DIM + sch * 8;
    }
#pragma unroll
    for (int hb = 0; hb < 2; hb++)
#pragma unroll
        for (int j = 0; j < 2; j++) {
            int row = nbase + hb * 128 + wv * 16 + j * 8 + srow;
            if (row > WGU_ROWS - 1) row = WGU_ROWS - 1;   // clamp; garbage guarded at epilogue
            bpg[hb][j] = wb + (size_t)row * DIM + sch * 8;
        }

    __bf16* a0  = &lds[0][0];
    __bf16* a1  = &lds[1][0];
    __bf16* b0b = &lds[0][MT * BK];
    __bf16* b1b = &lds[1][MT * BK];

    v4f acc[4][4];
#pragma unroll
    for (int i = 0; i < 4; i++)
#pragma unroll
        for (int j = 0; j < 4; j++) acc[i][j] = (v4f){0.f, 0.f, 0.f, 0.f};

    // prologue: tile0 (A0,B0,B1,A1) + tile1 (A0,B0,B1) = 11 loads; vmcnt(5) lands tile0's 6
    STGA(a0, 0); STGB(b0b, 0); STGB(b0b, 1); STGA(a0, 1);
    STGA(a1, 0); STGB(b1b, 0); STGB(b1b, 1);
    asm volatile("s_waitcnt vmcnt(5)" ::: "memory");
    __builtin_amdgcn_s_barrier();

    int fm = ln & 15, kq = ln >> 4, f7 = fm & 7;
    int wsm = wv >> 2, wsn = wv & 3;

#pragma unroll 1
    for (int t = 0; t < NT2; ++t) {
        __bf16* cA = (t & 1) ? a1 : a0;
        __bf16* cB = (t & 1) ? b1b : b0b;
        __bf16* nA = (t & 1) ? a0 : a1;
        bool s1 = (t + 1 < NT2), s2 = (t + 2 < NT2);

        v8bf af[2][2], bf0[2][2], bf1[2][2];

        // ---- P1: Q(0,0): read A0-frags + B0-frags; stage A1(t+1) ----
#pragma unroll
        for (int mi = 0; mi < 2; mi++)
#pragma unroll
            for (int ks = 0; ks < 2; ks++) {
                int R = wsm * 32 + mi * 16 + fm;
                af[mi][ks] = *(const v8bf*)&cA[R * BK + (((ks * 4 + kq) ^ f7) * 8)];
            }
#pragma unroll
        for (int nj = 0; nj < 2; nj++)
#pragma unroll
            for (int ks = 0; ks < 2; ks++) {
                int S = wsn * 32 + nj * 16 + fm;
                bf0[nj][ks] = *(const v8bf*)&cB[S * BK + (((ks * 4 + kq) ^ f7) * 8)];
            }
        if (s1) STGA(nA, 1);
        __builtin_amdgcn_s_barrier();
        __builtin_amdgcn_s_setprio(1);
#pragma unroll
        for (int mi = 0; mi < 2; mi++)
#pragma unroll
            for (int nj = 0; nj < 2; nj++)
#pragma unroll
                for (int ks = 0; ks < 2; ks++)
                    acc[mi][nj] = __builtin_amdgcn_mfma_f32_16x16x32_bf16(af[mi][ks], bf0[nj][ks], acc[mi][nj], 0, 0, 0);
        __builtin_amdgcn_s_setprio(0);
        __builtin_amdgcn_s_barrier();

        // ---- P2: Q(0,1): read B1-frags; stage A0(t+2) ----
#pragma unroll
        for (int nj = 0; nj < 2; nj++)
#pragma unroll
            for (int ks = 0; ks < 2; ks++) {
                int S = 128 + wsn * 32 + nj * 16 + fm;
                bf1[nj][ks] = *(const v8bf*)&cB[S * BK + (((ks * 4 + kq) ^ f7) * 8)];
            }
        if (s2) STGA(cA, 0);
        __builtin_amdgcn_s_barrier();
        __builtin_amdgcn_s_setprio(1);
#pragma unroll
        for (int mi = 0; mi < 2; mi++)
#pragma unroll
            for (int nj = 0; nj < 2; nj++)
#pragma unroll
                for (int ks = 0; ks < 2; ks++)
                    acc[mi][2 + nj] = __builtin_amdgcn_mfma_f32_16x16x32_bf16(af[mi][ks], bf1[nj][ks], acc[mi][2 + nj], 0, 0, 0);
        __builtin_amdgcn_s_setprio(0);
        __builtin_amdgcn_s_barrier();

        // ---- P3: Q(1,0): read A1-frags (reuse af regs); stage B0(t+2) ----
#pragma unroll
        for (int mi = 0; mi < 2; mi++)
#pragma unroll
            for (int ks = 0; ks < 2; ks++) {
                int R = 64 + wsm * 32 + mi * 16 + fm;
                af[mi][ks] = *(const v8bf*)&cA[R * BK + (((ks * 4 + kq) ^ f7) * 8)];
            }
        if (s2) STGB(cB, 0);
        __builtin_amdgcn_s_barrier();
        __builtin_amdgcn_s_setprio(1);
#pragma unroll
        for (int mi = 0; mi < 2; mi++)
#pragma unroll
            for (int nj = 0; nj < 2; nj++)
#pragma unroll
                for (int ks = 0; ks < 2; ks++)
                    acc[2 + mi][nj] = __builtin_amdgcn_mfma_f32_16x16x32_bf16(af[mi][ks], bf0[nj][ks], acc[2 + mi][nj], 0, 0, 0);
        __builtin_amdgcn_s_setprio(0);
        __builtin_amdgcn_s_barrier();

        // ---- P4: Q(1,1): no reads; stage B1(t+2); boundary vmcnt ----
        if (s2) STGB(cB, 1);
        __builtin_amdgcn_s_barrier();
        __builtin_amdgcn_s_setprio(1);
#pragma unroll
        for (int mi = 0; mi < 2; mi++)
#pragma unroll
            for (int nj = 0; nj < 2; nj++)
#pragma unroll
                for (int ks = 0; ks < 2; ks++)
                    acc[2 + mi][2 + nj] = __builtin_amdgcn_mfma_f32_16x16x32_bf16(af[mi][ks], bf1[nj][ks], acc[2 + mi][2 + nj], 0, 0, 0);
        __builtin_amdgcn_s_setprio(0);
        if (t == NT2 - 2)      asm volatile("s_waitcnt vmcnt(0)" ::: "memory");
        else if (t < NT2 - 2)  asm volatile("s_waitcnt vmcnt(5)" ::: "memory");
        __builtin_amdgcn_s_barrier();
    }

    // ---- epilogue: even n-frag = gate, odd = up, same lane/rows/cols -> silu in regs ----
#pragma unroll
    for (int mh = 0; mh < 2; mh++)
#pragma unroll
        for (int mi = 0; mi < 2; mi++) {
            int rbase = mbase + mh * 64 + wsm * 32 + mi * 16 + kq * 4;
#pragma unroll
            for (int nh = 0; nh < 2; nh++) {
                int f = fbase + (nh * 4 + wsn) * 16 + fm;
                if (f < FDIM) {
                    v4f g = acc[mh * 2 + mi][nh * 2 + 0];
                    v4f u = acc[mh * 2 + mi][nh * 2 + 1];
#pragma unroll
                    for (int r = 0; r < 4; r++) {
                        float gg = g[r];
                        float h = gg / (1.f + __expf(-gg)) * u[r];
                        Hb[(size_t)(rbase + r) * FDIM + f] = (__bf16)h;
                    }
                }
            }
        }
}

// ---------------- pass B: Y = H @ Wd (unchanged 128x128 structure) ----------------
__global__ __launch_bounds__(256, 2) void gemm_b(
    const __bf16* __restrict__ Hb, const __bf16* __restrict__ wd_t,
    const int* __restrict__ hdr, float* __restrict__ Y)
{
    int mbase = blockIdx.y * MT;
    if (mbase >= hdr[24]) return;
    const __bf16* wd = wd_t;
    int e = 0;
    while (mbase >= hdr[17 + e]) e++;
    wd += (size_t)e * FDIM * DIM;
    int nbase = blockIdx.x * NT;

    __shared__ __align__(16) __bf16 sA[MT * BK];
    __shared__ __align__(16) __bf16 sB[NT * BK];

    int tid = threadIdx.x, wave = tid >> 6, lane = tid & 63;
    int rsub = lane >> 3;
    int gch  = (lane & 7) ^ rsub;

    const __bf16 *agp[4], *bgp[4];
    __bf16 *ldA[4], *ldB[4];
#pragma unroll
    for (int i = 0; i < 4; i++) {
        int row = wave * 32 + i * 8 + rsub;
        agp[i] = Hb + (size_t)(mbase + row) * FDIM + gch * 8;
        bgp[i] = wd + (size_t)(nbase + row) * FDIM + gch * 8;
        ldA[i] = sA + (wave * 32 + i * 8) * BK;
        ldB[i] = sB + (wave * 32 + i * 8) * BK;
    }

    int wm = (wave >> 1) * 64, wn = (wave & 1) * 64;
    int fm = lane & 15, kq = lane >> 4;

    v4f acc[4][4];
#pragma unroll
    for (int i = 0; i < 4; i++)
#pragma unroll
        for (int j = 0; j < 4; j++) acc[i][j] = (v4f){0.f, 0.f, 0.f, 0.f};

    for (int k0 = 0; k0 < FDIM; k0 += BK) {
#pragma unroll
        for (int i = 0; i < 4; i++) {
            gld16(agp[i], ldA[i]);
            gld16(bgp[i], ldB[i]);
            agp[i] += BK; bgp[i] += BK;
        }
        __syncthreads();

#pragma unroll
        for (int h = 0; h < 2; h++) {
            v8bf af[4], bf_[4];
#pragma unroll
            for (int i = 0; i < 4; i++) {
                int row = wm + i * 16 + fm;
                af[i] = *(v8bf*)&sA[row * BK + (((kq + 4 * h) ^ (fm & 7)) * 8)];
            }
#pragma unroll
            for (int j = 0; j < 4; j++) {
                int row = wn + j * 16 + fm;
                bf_[j] = *(v8bf*)&sB[row * BK + (((kq + 4 * h) ^ (fm & 7)) * 8)];
            }
#pragma unroll
            for (int i = 0; i < 4; i++)
#pragma unroll
                for (int j = 0; j < 4; j++)
                    acc[i][j] = __builtin_amdgcn_mfma_f32_16x16x32_bf16(af[i], bf_[j], acc[i][j], 0, 0, 0);
        }
        __syncthreads();
    }

    int rq = kq * 4;
#pragma unroll
    for (int i = 0; i < 4; i++) {
#pragma unroll
        for (int r = 0; r < 4; r++) {
            int row = mbase + wm + i * 16 + rq + r;
            size_t yb = (size_t)row * DIM + nbase + wn + fm;
#pragma unroll
            for (int j = 0; j < 4; j++)
                Y[yb + j * 16] = acc[i][j][r];
        }
    }
}

// ---------------- combine: out[t] = w0*Y[s0] + w1*Y[s1] ----------------
__global__ __launch_bounds__(256) void combine_kernel(
    const float* __restrict__ Y, const int* __restrict__ slots,
    const float* __restrict__ wgt, float* __restrict__ out)
{
    int t = blockIdx.x;
    int d = threadIdx.x * 4;
    int s0 = slots[t * 2], s1 = slots[t * 2 + 1];
    float w0 = wgt[s0], w1 = wgt[s1];
    float4 y0 = *(const float4*)&Y[(size_t)s0 * DIM + d];
    float4 y1 = *(const float4*)&Y[(size_t)s1 * DIM + d];
    float4 o;
    o.x = w0 * y0.x + w1 * y1.x;
    o.y = w0 * y0.y + w1 * y1.y;
    o.z = w0 * y0.z + w1 * y1.z;
    o.w = w0 * y0.w + w1 * y1.w;
    *(float4*)&out[(size_t)t * DIM + d] = o;
}

extern "C" void kernel_launch(void* const* d_in, const int* in_sizes, int n_in,
                              void* d_out, int out_size, void* d_ws, size_t ws_size,
                              hipStream_t stream)
{
    const float* x      = (const float*)d_in[0];
    const float* gate_w = (const float*)d_in[1];
    const float* w_gate = (const float*)d_in[2];
    const float* w_up   = (const float*)d_in[3];
    const float* w_down = (const float*)d_in[4];
    float* out = (float*)d_out;

    char* ws = (char*)d_ws;
    int*   hdr      = (int*)(ws + WS_HDR);
    float* load_sum = (float*)(ws + WS_LOADSUM);
    int*   ids      = (int*)(ws + WS_IDS);
    float* probs    = (float*)(ws + WS_PROBS);
    int*   perm     = (int*)(ws + WS_PERM);
    float* wgt      = (float*)(ws + WS_WGT);
    __bf16* Hb      = (__bf16*)(ws + WS_H);
    __bf16* xb      = (__bf16*)(ws + WS_XBF);
    __bf16* wgu_t   = (__bf16*)(ws + WS_WGU);
    __bf16* wd_t    = (__bf16*)(ws + WS_WD_T);
    float*  Y       = (float*)(ws + WS_Y);

    hipMemsetAsync(ws, 0, 512, stream);
    hipMemsetAsync(ws + WS_PERM, 0, 2 * 17408 * 4, stream);

    gate_kernel<<<256, 256, 0, stream>>>(x, gate_w, hdr, load_sum, ids, probs, xb);
    scan_kernel<<<1, 64, 0, stream>>>(hdr, load_sum, out + (size_t)N_TOK * DIM);
    scatter_kernel<<<N_TOK / 256, 256, 0, stream>>>(nullptr, probs, hdr, perm, wgt, ids);

    transpose_gu<<<dim3(FDIM / 64, DIM / 64, 16), 256, 0, stream>>>(w_gate, w_up, wgu_t);
    transpose_d<<<dim3(DIM / 64, FDIM / 64, 8), 256, 0, stream>>>(w_down, wd_t);

    gemm_a8<<<dim3(22, 136), 512, 0, stream>>>(xb, wgu_t, hdr, perm, Hb);
    gemm_b<<<dim3(DIM / NT, 136), 256, 0, stream>>>(Hb, wd_t, hdr, Y);
    combine_kernel<<<N_TOK, 256, 0, stream>>>(Y, ids, wgt, out);
}

// Round 3
// 701.722 us; speedup vs baseline: 1.1431x; 1.0619x over previous
//
#include <hip/hip_runtime.h>
#include <hip/hip_bf16.h>
#include <math.h>

#define N_TOK 8192
#define DIM   1024
#define NEXP  8
#define FDIM  2752
#define BK    64
#define MT    128
#define NT    128
#define WGU_ROWS 5504          // 2*FDIM interleaved rows per expert
#define ABOFF (256 * BK)       // B region offset (elements) within one LDS buffer

typedef __bf16 v8bf __attribute__((ext_vector_type(8)));
typedef __bf16 v4bf __attribute__((ext_vector_type(4)));
typedef float  v4f  __attribute__((ext_vector_type(4)));

// ws layout (bytes) — unchanged from passing round-2 kernel
#define WS_HDR     0
#define WS_LOADSUM 256
#define WS_IDS     512
#define WS_PROBS   66048
#define WS_PERM    131584
#define WS_WGT     201216
#define WS_H       270848            // bf16[17408*FDIM]
#define WS_XBF     96084480ull       // bf16[N_TOK*DIM]
#define WS_WGU     112861696ull      // bf16[8*WGU_ROWS*DIM]
#define WS_WD_T    203039232ull      // bf16[8*FDIM*DIM]
#define WS_Y       112861696ull      // fp32[17408*1024] overlays WGU (dead after gemm_a)

__device__ __forceinline__ void gld16(const __bf16* g, __bf16* l) {
    __builtin_amdgcn_global_load_lds(
        (const __attribute__((address_space(1))) void*)g,
        (__attribute__((address_space(3))) void*)l, 16, 0, 0);
}

// ---------------- gating (grid-stride: 256 blocks x 8 passes) ----------------
__global__ __launch_bounds__(256) void gate_kernel(
    const float* __restrict__ x, const float* __restrict__ gw,
    int* __restrict__ hdr, float* __restrict__ load_sum,
    int* __restrict__ ids, float* __restrict__ probs, __bf16* __restrict__ xb)
{
    __shared__ float s_load[NEXP];
    __shared__ int   s_cnt[NEXP];
    int tid = threadIdx.x;
    if (tid < NEXP) { s_load[tid] = 0.f; s_cnt[tid] = 0; }
    __syncthreads();

    int wave = tid >> 6, lane = tid & 63;
#pragma unroll 1
    for (int pass = 0; pass < 8; ++pass) {
        int tok = (blockIdx.x * 8 + pass) * 4 + wave;
        float acc[NEXP];
#pragma unroll
        for (int e = 0; e < NEXP; e++) acc[e] = 0.f;
        const float4* xr4 = (const float4*)(x + (size_t)tok * DIM);
#pragma unroll
        for (int it = 0; it < 4; it++) {
            int d4 = it * 64 + lane;
            float4 xv = xr4[d4];
            v4bf vb;
            vb[0] = (__bf16)xv.x; vb[1] = (__bf16)xv.y;
            vb[2] = (__bf16)xv.z; vb[3] = (__bf16)xv.w;
            *(v4bf*)&xb[(size_t)tok * DIM + d4 * 4] = vb;
            int d = d4 * 4;
#pragma unroll
            for (int e = 0; e < NEXP; e++)
                acc[e] += xv.x * gw[d * NEXP + e] + xv.y * gw[(d + 1) * NEXP + e]
                        + xv.z * gw[(d + 2) * NEXP + e] + xv.w * gw[(d + 3) * NEXP + e];
        }
#pragma unroll
        for (int e = 0; e < NEXP; e++) {
#pragma unroll
            for (int off = 32; off > 0; off >>= 1) acc[e] += __shfl_xor(acc[e], off, 64);
        }
        if (lane == 0) {
            float m = acc[0];
#pragma unroll
            for (int e = 1; e < NEXP; e++) m = fmaxf(m, acc[e]);
            float p[NEXP], s = 0.f;
#pragma unroll
            for (int e = 0; e < NEXP; e++) { p[e] = __expf(acc[e] - m); s += p[e]; }
            float inv = 1.f / s;
#pragma unroll
            for (int e = 0; e < NEXP; e++) p[e] *= inv;
            int i1 = 0; float p1 = p[0];
#pragma unroll
            for (int e = 1; e < NEXP; e++) if (p[e] > p1) { p1 = p[e]; i1 = e; }
            int i2 = -1; float p2 = -1.f;
#pragma unroll
            for (int e = 0; e < NEXP; e++) if (e != i1 && p[e] > p2) { p2 = p[e]; i2 = e; }
            float rs = 1.f / (p1 + p2 + 1e-8f);
            ids[tok * 2] = i1;  ids[tok * 2 + 1] = i2;
            probs[tok * 2] = p1 * rs;  probs[tok * 2 + 1] = p2 * rs;
#pragma unroll
            for (int e = 0; e < NEXP; e++) atomicAdd(&s_load[e], p[e]);
            atomicAdd(&s_cnt[i1], 1);  atomicAdd(&s_cnt[i2], 1);
        }
    }
    __syncthreads();
    if (tid < NEXP) {
        atomicAdd(&load_sum[tid], s_load[tid]);
        atomicAdd(&hdr[tid], s_cnt[tid]);
    }
}

// ---------------- scan ----------------
__global__ void scan_kernel(int* __restrict__ hdr, const float* __restrict__ load_sum,
                            float* __restrict__ aux_out)
{
    if (threadIdx.x == 0) {
        int off = 0;
        float aux = 0.f;
        for (int e = 0; e < NEXP; e++) {
            hdr[16 + e] = off;
            int c = hdr[e];
            off += (c + 127) & ~127;
            aux += ((float)c / (float)(N_TOK * 2)) * (load_sum[e] / (float)N_TOK);
        }
        hdr[24] = off;
        *aux_out = 0.01f * 8.f * aux;
    }
}

// ---------------- scatter: LDS-aggregated cursors ----------------
__global__ __launch_bounds__(256) void scatter_kernel(
    const int* __restrict__ probs_dummy, const float* __restrict__ probs,
    int* __restrict__ hdr, int* __restrict__ perm, float* __restrict__ wgt,
    int* __restrict__ ids)
{
    __shared__ int s_cnt[NEXP], s_base[NEXP];
    int tid = threadIdx.x;
    if (tid < NEXP) s_cnt[tid] = 0;
    __syncthreads();
    int t = blockIdx.x * 256 + tid;
    int e0 = ids[t * 2], e1 = ids[t * 2 + 1];
    int l0 = atomicAdd(&s_cnt[e0], 1);
    int l1 = atomicAdd(&s_cnt[e1], 1);
    __syncthreads();
    if (tid < NEXP) s_base[tid] = atomicAdd(&hdr[8 + tid], s_cnt[tid]);
    __syncthreads();
    int s0 = hdr[16 + e0] + s_base[e0] + l0;
    int s1 = hdr[16 + e1] + s_base[e1] + l1;
    perm[s0] = t;  wgt[s0] = probs[t * 2];
    perm[s1] = t;  wgt[s1] = probs[t * 2 + 1];
    ids[t * 2] = s0;  ids[t * 2 + 1] = s1;
}

// ---------------- transpose+cast ----------------
__device__ __forceinline__ void tc_body(const float* __restrict__ s, __bf16* __restrict__ d,
                                        int R, int C, int cb, int rb, int tid)
{
    __shared__ float tile[64][65];
    int c4 = (tid & 15) * 4, rr = tid >> 4;
#pragma unroll
    for (int p = 0; p < 4; p++) {
        int r = p * 16 + rr;
        float4 v = *(const float4*)&s[(size_t)(rb + r) * C + cb + c4];
        tile[r][c4] = v.x; tile[r][c4 + 1] = v.y; tile[r][c4 + 2] = v.z; tile[r][c4 + 3] = v.w;
    }
    __syncthreads();
#pragma unroll
    for (int p = 0; p < 2; p++) {
        int cc = p * 32 + (tid >> 3);
        int rr0 = (tid & 7) * 8;
        v8bf v;
#pragma unroll
        for (int j = 0; j < 8; j++) v[j] = (__bf16)tile[rr0 + j][cc];
        *(v8bf*)&d[(size_t)(cb + cc) * R + rb + rr0] = v;
    }
}

// wg/wu -> interleaved WGU: row(f, which) = (f>>4)*32 + (f&15) + which*16
__global__ __launch_bounds__(256) void transpose_gu(
    const float* __restrict__ wg, const float* __restrict__ wu,
    __bf16* __restrict__ wgu)
{
    int which = blockIdx.z >> 3, e = blockIdx.z & 7;
    const float* s = (which ? wu : wg) + (size_t)e * DIM * FDIM;
    __bf16* d = wgu + (size_t)e * WGU_ROWS * DIM;

    __shared__ float tile[64][65];
    int cb = blockIdx.x * 64, rb = blockIdx.y * 64, tid = threadIdx.x;
    int c4 = (tid & 15) * 4, rr = tid >> 4;
#pragma unroll
    for (int p = 0; p < 4; p++) {
        int r = p * 16 + rr;
        float4 v = *(const float4*)&s[(size_t)(rb + r) * FDIM + cb + c4];
        tile[r][c4] = v.x; tile[r][c4 + 1] = v.y; tile[r][c4 + 2] = v.z; tile[r][c4 + 3] = v.w;
    }
    __syncthreads();
#pragma unroll
    for (int p = 0; p < 2; p++) {
        int cc = p * 32 + (tid >> 3);
        int rr0 = (tid & 7) * 8;
        v8bf v;
#pragma unroll
        for (int j = 0; j < 8; j++) v[j] = (__bf16)tile[rr0 + j][cc];
        int f = cb + cc;
        int fr = ((f >> 4) << 5) + (f & 15) + which * 16;
        *(v8bf*)&d[(size_t)fr * DIM + rb + rr0] = v;
    }
}

__global__ __launch_bounds__(256) void transpose_d(
    const float* __restrict__ wd, __bf16* __restrict__ wdt)
{
    size_t slab = (size_t)blockIdx.z * DIM * FDIM;
    tc_body(wd + slab, wdt + slab, FDIM, DIM, blockIdx.x * 64, blockIdx.y * 64, threadIdx.x);
}

// ---------------- pass A: m201-geometry 8-phase, BM=256 x BN=256(g|u interleaved) x BK=64 ----------------
// 8 waves 2M x 4N; per-wave 128x64; 16 MFMA/phase; 2 K-tiles per 8-phase iteration.
// Staging slots (one half-tile = 2 gld16 per phase):
//   P1: buf1.B1<-t(2i+1)  P2: buf1.A1<-t(2i+1)  P3..P6: buf0.{B0,A0,B1,A1}<-t(2i+2)
//   P7: buf1.B0<-t(2i+3)  P8: buf1.A0<-t(2i+3)
// vmcnt(4) at P4 (lands tile 2i+1) and P8 (lands tile 2i+2); vmcnt(0) at P4 of last iter.
#define STGAH(buf, h, kk) do { \
    gld16(aA[h][0] + (kk), &lds[buf][((h) * 128 +  0 + wv * 8) * BK]); \
    gld16(aA[h][1] + (kk), &lds[buf][((h) * 128 + 64 + wv * 8) * BK]); } while (0)
#define STGBH(buf, h, kk) do { \
    gld16(bB[h][0] + (kk), &lds[buf][ABOFF + ((h) * 128 +  0 + wv * 8) * BK]); \
    gld16(bB[h][1] + (kk), &lds[buf][ABOFF + ((h) * 128 + 64 + wv * 8) * BK]); } while (0)
#define RD_A(b, qm) do { \
    _Pragma("unroll") for (int mi = 0; mi < 4; mi++) \
    _Pragma("unroll") for (int ks = 0; ks < 2; ks++) { \
        int R = wsm * 128 + (qm) * 64 + mi * 16 + fm; \
        af[mi][ks] = *(const v8bf*)&lds[b][R * BK + (((ks * 4 + kq) ^ f7) * 8)]; } \
} while (0)
#define RD_B(b, qn, dst) do { \
    _Pragma("unroll") for (int nj = 0; nj < 2; nj++) \
    _Pragma("unroll") for (int ks = 0; ks < 2; ks++) { \
        int S = wsn * 64 + (qn) * 32 + nj * 16 + fm; \
        dst[nj][ks] = *(const v8bf*)&lds[b][ABOFF + S * BK + (((ks * 4 + kq) ^ f7) * 8)]; } \
} while (0)
#define MMQ(qm0, bfq, qn) do { \
    _Pragma("unroll") for (int mi = 0; mi < 4; mi++) \
    _Pragma("unroll") for (int nj = 0; nj < 2; nj++) \
    _Pragma("unroll") for (int ks = 0; ks < 2; ks++) \
        acc[(qm0) + mi][(qn) * 2 + nj] = __builtin_amdgcn_mfma_f32_16x16x32_bf16( \
            af[mi][ks], bfq[nj][ks], acc[(qm0) + mi][(qn) * 2 + nj], 0, 0, 0); \
} while (0)
#define PH_MID() do { __builtin_amdgcn_s_barrier(); \
    asm volatile("s_waitcnt lgkmcnt(0)" ::: "memory"); \
    __builtin_amdgcn_s_setprio(1); } while (0)
#define PH_END() do { __builtin_amdgcn_s_setprio(0); \
    __builtin_amdgcn_s_barrier(); } while (0)

__global__ __launch_bounds__(512, 1) void gemm_a256(
    const __bf16* __restrict__ xb, const __bf16* __restrict__ wgu,
    const int* __restrict__ hdr, const int* __restrict__ perm,
    __bf16* __restrict__ Hb)
{
    // tile-table walk: blockIdx.y -> (expert e, mbase, mrows in {128,256})
    int ty = blockIdx.y;
    int e = -1, mbase = 0, mrows = 0, acct = 0;
    for (int ee = 0; ee < NEXP; ee++) {
        int s = hdr[16 + ee], en = hdr[17 + ee];
        int nt = (en - s + 255) >> 8;
        if (ty < acct + nt) {
            e = ee; mbase = s + (ty - acct) * 256;
            mrows = en - mbase; if (mrows > 256) mrows = 256;
            break;
        }
        acct += nt;
    }
    if (e < 0) return;

    const __bf16* wb = wgu + (size_t)e * WGU_ROWS * DIM;
    int nbase = blockIdx.x * 256;
    int fbase = blockIdx.x * 128;
    int total = hdr[24];

    __shared__ __align__(16) __bf16 lds[2][512 * BK];   // 128 KiB

    int tid = threadIdx.x, wv = tid >> 6, ln = tid & 63;
    int r64 = tid >> 3;                    // staging row within 64-row group
    int ch  = (tid & 7) ^ (r64 & 7);       // swizzled global col-chunk

    const __bf16 *aA[2][2], *bB[2][2];
#pragma unroll
    for (int h = 0; h < 2; h++)
#pragma unroll
        for (int j = 0; j < 2; j++) {
            int row = mbase + h * 128 + j * 64 + r64;
            row = row < total ? row : total - 1;     // tail-tile clamp (stores guarded)
            aA[h][j] = xb + (size_t)perm[row] * DIM + ch * 8;
            int wrow = nbase + h * 128 + j * 64 + r64;
            if (wrow > WGU_ROWS - 1) wrow = WGU_ROWS - 1;
            bB[h][j] = wb + (size_t)wrow * DIM + ch * 8;
        }

    int fm = ln & 15, kq = ln >> 4, f7 = fm & 7;
    int wsm = wv >> 2, wsn = wv & 3;

    v4f acc[8][4];
#pragma unroll
    for (int i = 0; i < 8; i++)
#pragma unroll
        for (int j = 0; j < 4; j++) acc[i][j] = (v4f){0.f, 0.f, 0.f, 0.f};

    v8bf af[4][2], bf0[2][2], bf1[2][2];

    // prologue: tile0 all 4 halves into buf0 (8 loads) + tile1 B0,A0 into buf1 (4 loads)
    STGAH(0, 0, 0); STGAH(0, 1, 0); STGBH(0, 0, 0); STGBH(0, 1, 0);
    STGBH(1, 0, BK); STGAH(1, 0, BK);
    asm volatile("s_waitcnt vmcnt(4)" ::: "memory");
    __builtin_amdgcn_s_barrier();

#pragma unroll 1
    for (int i = 0; i < 8; ++i) {
        int k1 = (2 * i + 1) * BK, k2 = (2 * i + 2) * BK, k3 = (2 * i + 3) * BK;
        bool st = (i < 7);

        // ===== K-tile 2i from buf0 =====
        // P1
        RD_A(0, 0); RD_B(0, 0, bf0);
        STGBH(1, 1, k1);
        PH_MID(); MMQ(0, bf0, 0); PH_END();
        // P2
        RD_B(0, 1, bf1);
        STGAH(1, 1, k1);
        PH_MID(); MMQ(0, bf1, 1); PH_END();
        // P3
        RD_A(0, 1);
        if (st) STGBH(0, 0, k2);
        PH_MID(); MMQ(4, bf0, 0); PH_END();
        // P4
        if (st) STGAH(0, 0, k2);
        __builtin_amdgcn_s_barrier();
        __builtin_amdgcn_s_setprio(1);
        MMQ(4, bf1, 1);
        __builtin_amdgcn_s_setprio(0);
        if (st) asm volatile("s_waitcnt vmcnt(4)" ::: "memory");
        else    asm volatile("s_waitcnt vmcnt(0)" ::: "memory");
        __builtin_amdgcn_s_barrier();

        // ===== K-tile 2i+1 from buf1 =====
        // P5
        RD_A(1, 0); RD_B(1, 0, bf0);
        if (st) STGBH(0, 1, k2);
        PH_MID(); MMQ(0, bf0, 0); PH_END();
        // P6
        RD_B(1, 1, bf1);
        if (st) STGAH(0, 1, k2);
        PH_MID(); MMQ(0, bf1, 1); PH_END();
        // P7
        RD_A(1, 1);
        if (st) STGBH(1, 0, k3);
        PH_MID(); MMQ(4, bf0, 0); PH_END();
        // P8
        if (st) STGAH(1, 0, k3);
        __builtin_amdgcn_s_barrier();
        __builtin_amdgcn_s_setprio(1);
        MMQ(4, bf1, 1);
        __builtin_amdgcn_s_setprio(0);
        if (st) asm volatile("s_waitcnt vmcnt(4)" ::: "memory");
        __builtin_amdgcn_s_barrier();
    }

    // ---- epilogue: even n-frag = gate, odd = up; silu in regs; tail-tile store guard ----
#pragma unroll
    for (int qm = 0; qm < 2; qm++) {
        if (wsm * 128 + qm * 64 >= mrows) continue;
#pragma unroll
        for (int mi = 0; mi < 4; mi++) {
            int rbase = mbase + wsm * 128 + qm * 64 + mi * 16 + kq * 4;
#pragma unroll
            for (int qn = 0; qn < 2; qn++) {
                int f = fbase + (wsn * 2 + qn) * 16 + fm;
                if (f < FDIM) {
                    v4f g = acc[qm * 4 + mi][qn * 2 + 0];
                    v4f u = acc[qm * 4 + mi][qn * 2 + 1];
#pragma unroll
                    for (int r = 0; r < 4; r++) {
                        float gg = g[r];
                        float h = gg / (1.f + __expf(-gg)) * u[r];
                        Hb[(size_t)(rbase + r) * FDIM + f] = (__bf16)h;
                    }
                }
            }
        }
    }
}

// ---------------- pass B: Y = H @ Wd (unchanged 128x128 structure) ----------------
__global__ __launch_bounds__(256, 2) void gemm_b(
    const __bf16* __restrict__ Hb, const __bf16* __restrict__ wd_t,
    const int* __restrict__ hdr, float* __restrict__ Y)
{
    int mbase = blockIdx.y * MT;
    if (mbase >= hdr[24]) return;
    const __bf16* wd = wd_t;
    int e = 0;
    while (mbase >= hdr[17 + e]) e++;
    wd += (size_t)e * FDIM * DIM;
    int nbase = blockIdx.x * NT;

    __shared__ __align__(16) __bf16 sA[MT * BK];
    __shared__ __align__(16) __bf16 sB[NT * BK];

    int tid = threadIdx.x, wave = tid >> 6, lane = tid & 63;
    int rsub = lane >> 3;
    int gch  = (lane & 7) ^ rsub;

    const __bf16 *agp[4], *bgp[4];
    __bf16 *ldA[4], *ldB[4];
#pragma unroll
    for (int i = 0; i < 4; i++) {
        int row = wave * 32 + i * 8 + rsub;
        agp[i] = Hb + (size_t)(mbase + row) * FDIM + gch * 8;
        bgp[i] = wd + (size_t)(nbase + row) * FDIM + gch * 8;
        ldA[i] = sA + (wave * 32 + i * 8) * BK;
        ldB[i] = sB + (wave * 32 + i * 8) * BK;
    }

    int wm = (wave >> 1) * 64, wn = (wave & 1) * 64;
    int fm = lane & 15, kq = lane >> 4;

    v4f acc[4][4];
#pragma unroll
    for (int i = 0; i < 4; i++)
#pragma unroll
        for (int j = 0; j < 4; j++) acc[i][j] = (v4f){0.f, 0.f, 0.f, 0.f};

    for (int k0 = 0; k0 < FDIM; k0 += BK) {
#pragma unroll
        for (int i = 0; i < 4; i++) {
            gld16(agp[i], ldA[i]);
            gld16(bgp[i], ldB[i]);
            agp[i] += BK; bgp[i] += BK;
        }
        __syncthreads();

#pragma unroll
        for (int h = 0; h < 2; h++) {
            v8bf af[4], bf_[4];
#pragma unroll
            for (int i = 0; i < 4; i++) {
                int row = wm + i * 16 + fm;
                af[i] = *(v8bf*)&sA[row * BK + (((kq + 4 * h) ^ (fm & 7)) * 8)];
            }
#pragma unroll
            for (int j = 0; j < 4; j++) {
                int row = wn + j * 16 + fm;
                bf_[j] = *(v8bf*)&sB[row * BK + (((kq + 4 * h) ^ (fm & 7)) * 8)];
            }
#pragma unroll
            for (int i = 0; i < 4; i++)
#pragma unroll
                for (int j = 0; j < 4; j++)
                    acc[i][j] = __builtin_amdgcn_mfma_f32_16x16x32_bf16(af[i], bf_[j], acc[i][j], 0, 0, 0);
        }
        __syncthreads();
    }

    int rq = kq * 4;
#pragma unroll
    for (int i = 0; i < 4; i++) {
#pragma unroll
        for (int r = 0; r < 4; r++) {
            int row = mbase + wm + i * 16 + rq + r;
            size_t yb = (size_t)row * DIM + nbase + wn + fm;
#pragma unroll
            for (int j = 0; j < 4; j++)
                Y[yb + j * 16] = acc[i][j][r];
        }
    }
}

// ---------------- combine: out[t] = w0*Y[s0] + w1*Y[s1] ----------------
__global__ __launch_bounds__(256) void combine_kernel(
    const float* __restrict__ Y, const int* __restrict__ slots,
    const float* __restrict__ wgt, float* __restrict__ out)
{
    int t = blockIdx.x;
    int d = threadIdx.x * 4;
    int s0 = slots[t * 2], s1 = slots[t * 2 + 1];
    float w0 = wgt[s0], w1 = wgt[s1];
    float4 y0 = *(const float4*)&Y[(size_t)s0 * DIM + d];
    float4 y1 = *(const float4*)&Y[(size_t)s1 * DIM + d];
    float4 o;
    o.x = w0 * y0.x + w1 * y1.x;
    o.y = w0 * y0.y + w1 * y1.y;
    o.z = w0 * y0.z + w1 * y1.z;
    o.w = w0 * y0.w + w1 * y1.w;
    *(float4*)&out[(size_t)t * DIM + d] = o;
}

extern "C" void kernel_launch(void* const* d_in, const int* in_sizes, int n_in,
                              void* d_out, int out_size, void* d_ws, size_t ws_size,
                              hipStream_t stream)
{
    const float* x      = (const float*)d_in[0];
    const float* gate_w = (const float*)d_in[1];
    const float* w_gate = (const float*)d_in[2];
    const float* w_up   = (const float*)d_in[3];
    const float* w_down = (const float*)d_in[4];
    float* out = (float*)d_out;

    char* ws = (char*)d_ws;
    int*   hdr      = (int*)(ws + WS_HDR);
    float* load_sum = (float*)(ws + WS_LOADSUM);
    int*   ids      = (int*)(ws + WS_IDS);
    float* probs    = (float*)(ws + WS_PROBS);
    int*   perm     = (int*)(ws + WS_PERM);
    float* wgt      = (float*)(ws + WS_WGT);
    __bf16* Hb      = (__bf16*)(ws + WS_H);
    __bf16* xb      = (__bf16*)(ws + WS_XBF);
    __bf16* wgu_t   = (__bf16*)(ws + WS_WGU);
    __bf16* wd_t    = (__bf16*)(ws + WS_WD_T);
    float*  Y       = (float*)(ws + WS_Y);

    hipMemsetAsync(ws, 0, 512, stream);
    hipMemsetAsync(ws + WS_PERM, 0, 2 * 17408 * 4, stream);

    gate_kernel<<<256, 256, 0, stream>>>(x, gate_w, hdr, load_sum, ids, probs, xb);
    scan_kernel<<<1, 64, 0, stream>>>(hdr, load_sum, out + (size_t)N_TOK * DIM);
    scatter_kernel<<<N_TOK / 256, 256, 0, stream>>>(nullptr, probs, hdr, perm, wgt, ids);

    transpose_gu<<<dim3(FDIM / 64, DIM / 64, 16), 256, 0, stream>>>(w_gate, w_up, wgu_t);
    transpose_d<<<dim3(DIM / 64, FDIM / 64, 8), 256, 0, stream>>>(w_down, wd_t);

    gemm_a256<<<dim3(22, 72), 512, 0, stream>>>(xb, wgu_t, hdr, perm, Hb);
    gemm_b<<<dim3(DIM / NT, 136), 256, 0, stream>>>(Hb, wd_t, hdr, Y);
    combine_kernel<<<N_TOK, 256, 0, stream>>>(Y, ids, wgt, out);
}